// Round 7
// baseline (270.446 us; speedup 1.0000x reference)
//
#include <hip/hip_runtime.h>
#include <hip/hip_bf16.h>
#include <stdint.h>

#define NTOK 8192
#define DIN  256
#define DOUT 256
#define NEXP 16
#define HID  512
#define NKA  (NTOK*2)   // total assignments
#define NBLK (NTOK/256) // routing blocks
#define MAXTILE 272     // sum ceil(Te/64) <= 16384/64 + 16

typedef __bf16 bf16x8 __attribute__((ext_vector_type(8)));
typedef float  f32x4  __attribute__((ext_vector_type(4)));

// ------- transpose-convert weights: src[k][e][n] fp32 -> dst[e][n][k] bf16 -------
__global__ void transpose_cvt_kernel(const float* __restrict__ src, __bf16* __restrict__ dst,
                                     int K, int N) {
  __shared__ float t[32][33];
  int e  = blockIdx.z;
  int k0 = blockIdx.x * 32, n0 = blockIdx.y * 32;
  int tx = threadIdx.x, ty = threadIdx.y;          // 32 x 8
  #pragma unroll
  for (int j = 0; j < 4; j++) {
    int kl = ty + j * 8;
    t[kl][tx] = src[(size_t)(k0 + kl) * (NEXP * N) + (size_t)e * N + n0 + tx];
  }
  __syncthreads();
  #pragma unroll
  for (int j = 0; j < 4; j++) {
    int nl = ty + j * 8;
    dst[(size_t)e * N * K + (size_t)(n0 + nl) * K + k0 + tx] = (__bf16)t[tx][nl];
  }
}

// ------- gate hidden GEMM, fp32: hg = relu(x @ gate_w + gate_b); also emits xb -------
// 128x64 tile, 256 threads, 8x4 per thread, BK=16. Blocks with blockIdx.y==0 also
// convert their A rows to bf16 (fuses the old cvt_x kernel).
__global__ __launch_bounds__(256) void gate_gemm_kernel(const float* __restrict__ A,
                                                        const float* __restrict__ B,
                                                        const float* __restrict__ bias,
                                                        float* __restrict__ out,
                                                        __bf16* __restrict__ xb) {
  const int K = DIN, N = HID;
  __shared__ float AlT[16][132];   // [k][m]
  __shared__ float Bl[16][68];     // [k][n]
  int m0 = blockIdx.x * 128, n0 = blockIdx.y * 64;
  int tid = threadIdx.x;
  int tx = tid & 15, ty = tid >> 4;
  float acc[8][4] = {};

  int am = tid >> 1, ak = (tid & 1) * 8;   // A: 128 rows x 16 k = 8 floats/thread
  int bk = tid >> 4, bn = (tid & 15) * 4;  // B: 16 k x 64 n = 1 float4/thread

  for (int kb = 0; kb < K; kb += 16) {
    float4 va0 = *(const float4*)&A[(size_t)(m0 + am) * K + kb + ak];
    float4 va1 = *(const float4*)&A[(size_t)(m0 + am) * K + kb + ak + 4];
    float4 vb  = *(const float4*)&B[(size_t)(kb + bk) * N + n0 + bn];
    if (blockIdx.y == 0) {
      bf16x8 xv;
      xv[0]=(__bf16)va0.x; xv[1]=(__bf16)va0.y; xv[2]=(__bf16)va0.z; xv[3]=(__bf16)va0.w;
      xv[4]=(__bf16)va1.x; xv[5]=(__bf16)va1.y; xv[6]=(__bf16)va1.z; xv[7]=(__bf16)va1.w;
      *(bf16x8*)&xb[(size_t)(m0 + am) * K + kb + ak] = xv;
    }
    __syncthreads();
    AlT[ak + 0][am] = va0.x; AlT[ak + 1][am] = va0.y;
    AlT[ak + 2][am] = va0.z; AlT[ak + 3][am] = va0.w;
    AlT[ak + 4][am] = va1.x; AlT[ak + 5][am] = va1.y;
    AlT[ak + 6][am] = va1.z; AlT[ak + 7][am] = va1.w;
    *(float4*)&Bl[bk][bn] = vb;
    __syncthreads();
    #pragma unroll
    for (int k = 0; k < 16; k++) {
      float4 a0 = *(const float4*)&AlT[k][ty * 8];
      float4 a1 = *(const float4*)&AlT[k][ty * 8 + 4];
      float4 b  = *(const float4*)&Bl[k][tx * 4];
      float av[8] = {a0.x,a0.y,a0.z,a0.w,a1.x,a1.y,a1.z,a1.w};
      float bv[4] = {b.x,b.y,b.z,b.w};
      #pragma unroll
      for (int i = 0; i < 8; i++)
        #pragma unroll
        for (int j = 0; j < 4; j++)
          acc[i][j] = fmaf(av[i], bv[j], acc[i][j]);
    }
  }
  float bb[4];
  #pragma unroll
  for (int j = 0; j < 4; j++) bb[j] = bias[n0 + tx * 4 + j];
  #pragma unroll
  for (int i = 0; i < 8; i++) {
    int m = m0 + ty * 8 + i;
    float4 o;
    o.x = fmaxf(acc[i][0] + bb[0], 0.f);
    o.y = fmaxf(acc[i][1] + bb[1], 0.f);
    o.z = fmaxf(acc[i][2] + bb[2], 0.f);
    o.w = fmaxf(acc[i][3] + bb[3], 0.f);
    *(float4*)&out[(size_t)m * N + n0 + tx * 4] = o;
  }
}

// ---------------- logits = hg @ gate_out_w + gate_out_b  (fp32) ----------------
__global__ __launch_bounds__(128) void logits_kernel(const float* __restrict__ hg,
                                                     const float* __restrict__ gw,
                                                     const float* __restrict__ gb,
                                                     float* __restrict__ logits) {
  __shared__ float hl[8][HID];
  __shared__ float wl[HID][16];
  int t0 = blockIdx.x * 8;
  int tid = threadIdx.x;
  for (int c = tid; c < 8 * (HID / 4); c += 128) {
    int row = c >> 7, col = (c & 127) * 4;
    *(float4*)&hl[row][col] = *(const float4*)&hg[(size_t)(t0 + row) * HID + col];
  }
  for (int c = tid; c < HID * 4; c += 128) {
    int k = c >> 2, e4 = (c & 3) * 4;
    *(float4*)&wl[k][e4] = *(const float4*)&gw[(size_t)k * 16 + e4];
  }
  __syncthreads();
  int tok = tid >> 4, e = tid & 15;
  float s = gb[e];
  #pragma unroll 8
  for (int k = 0; k < HID; k++) s = fmaf(hl[tok][k], wl[k][e], s);
  logits[(size_t)(t0 + tok) * 16 + e] = s;
}

// ---------------- top-2 + softmax + block-local histogram/ranks ----------------
__global__ __launch_bounds__(256) void top2_route_kernel(const float* __restrict__ logits,
                                                         int2* __restrict__ e01,
                                                         float2* __restrict__ g01,
                                                         int* __restrict__ lrank,
                                                         int* __restrict__ blockhist) {
  __shared__ int hist[NEXP];
  int tid = threadIdx.x;
  if (tid < NEXP) hist[tid] = 0;
  __syncthreads();
  int t = blockIdx.x * 256 + tid;
  float lv[16];
  const float4* lp = (const float4*)(logits + (size_t)t * 16);
  #pragma unroll
  for (int j = 0; j < 4; j++) { float4 v = lp[j]; lv[4*j]=v.x; lv[4*j+1]=v.y; lv[4*j+2]=v.z; lv[4*j+3]=v.w; }
  float v0 = -3.402823466e38f, v1 = -3.402823466e38f;
  int i0 = 0, i1 = 0;
  #pragma unroll
  for (int e = 0; e < 16; e++) {
    float v = lv[e];
    if (v > v0) { v1 = v0; i1 = i0; v0 = v; i0 = e; }
    else if (v > v1) { v1 = v; i1 = e; }
  }
  float ew = expf(v1 - v0);
  float inv = 1.f / (1.f + ew);
  e01[t] = make_int2(i0, i1);
  g01[t] = make_float2(inv, ew * inv);
  int r0 = atomicAdd(&hist[i0], 1);
  int r1 = atomicAdd(&hist[i1], 1);
  lrank[2 * t]     = r0;
  lrank[2 * t + 1] = r1;
  __syncthreads();
  if (tid < NEXP) blockhist[blockIdx.x * NEXP + tid] = hist[tid];
}

// ------- scan: expert offsets, per-(block,expert) base, and the flat TILE LIST -------
__global__ void scan2_kernel(const int* __restrict__ blockhist, int* __restrict__ offsets,
                             int* __restrict__ base, int* __restrict__ tile_e,
                             int* __restrict__ tile_mt, int* __restrict__ ntiles) {
  __shared__ int tot[NEXP];
  __shared__ int soff[NEXP + 1];
  __shared__ int tbase[NEXP];
  int e = threadIdx.x;
  if (e < NEXP) {
    int s = 0;
    for (int b = 0; b < NBLK; b++) s += blockhist[b * NEXP + e];
    tot[e] = s;
  }
  __syncthreads();
  if (e == 0) {
    int s = 0, tb = 0;
    for (int i = 0; i < NEXP; i++) {
      soff[i] = s; s += tot[i];
      tbase[i] = tb; tb += (tot[i] + 63) >> 6;
    }
    soff[NEXP] = s;
    *ntiles = tb;
  }
  __syncthreads();
  if (e < NEXP + 1) offsets[e] = soff[e];
  if (e < NEXP) {
    int s = soff[e];
    for (int b = 0; b < NBLK; b++) { base[b * NEXP + e] = s; s += blockhist[b * NEXP + e]; }
    int nt = (tot[e] + 63) >> 6, tb = tbase[e];
    for (int m = 0; m < nt; m++) { tile_e[tb + m] = e; tile_mt[tb + m] = m; }
  }
}

// ---------------- fill: atomic-free scatter using (base, lrank) ----------------
__global__ __launch_bounds__(256) void fill2_kernel(const int2* __restrict__ e01,
                                                    const int* __restrict__ lrank,
                                                    const int* __restrict__ base,
                                                    int* __restrict__ tok_sorted,
                                                    int* __restrict__ route_pos) {
  int b = blockIdx.x;
  int t = b * 256 + threadIdx.x;
  int2 e = e01[t];
  int p0 = base[b * NEXP + e.x] + lrank[2 * t];
  int p1 = base[b * NEXP + e.y] + lrank[2 * t + 1];
  tok_sorted[p0] = t; route_pos[2 * t]     = p0;
  tok_sorted[p1] = t; route_pos[2 * t + 1] = p1;
}

// ======== FUSED expert MLP: one block = 64 assignments through L1+L2+L3 ========
// 512 threads = 8 waves. h1/h2 live in ONE 33 KB LDS buffer (halves of the 512-wide
// hidden processed alternately). Weights stream L2->registers as B-fragments
// (each wave owns disjoint output cols -> no cross-wave weight reuse exists).
// A-operand: m = l16, k = quad*8 (bf16x8); C-layout: col = ni*16+l16, row = mi*16+quad*4+r.
__global__ __launch_bounds__(512, 2) void moe_mlp_kernel(
    const __bf16* __restrict__ xb,
    const __bf16* __restrict__ w1t, const float* __restrict__ b1,
    const __bf16* __restrict__ w2t, const float* __restrict__ b2,
    const __bf16* __restrict__ w3t, const float* __restrict__ b3,
    float* __restrict__ Y,
    const int* __restrict__ seg_off, const int* __restrict__ gather,
    const int* __restrict__ tile_e, const int* __restrict__ tile_mt,
    const int* __restrict__ ntiles) {
  int bx = blockIdx.x;
  if (bx >= *ntiles) return;
  const int e = tile_e[bx], mt = tile_mt[bx];
  const int off = seg_off[e], Te = seg_off[e + 1] - off;

  __shared__ __bf16 hbuf[64][264];   // +8 pad: b128 A-reads land 8 touches/bank (floor)

  const int tid = threadIdx.x;
  const int lane = tid & 63, w = tid >> 6;   // 8 waves
  const int l16 = lane & 15, quad = lane >> 4;

  // gathered x-row pointers for the 4 m-frags (per-lane rows)
  const __bf16* Ap[4];
  #pragma unroll
  for (int i = 0; i < 4; i++) {
    int m = mt * 64 + i * 16 + l16;
    int mr = m < Te ? m : Te - 1;
    Ap[i] = xb + (size_t)gather[off + mr] * DIN + quad * 8;
  }

  const __bf16* W1e = w1t + (size_t)e * HID * DIN;
  const __bf16* W2e = w2t + (size_t)e * HID * HID;
  const __bf16* W3e = w3t + (size_t)e * DOUT * HID;

  f32x4 acc2[4][4];
  #pragma unroll
  for (int i = 0; i < 4; i++)
    #pragma unroll
    for (int j = 0; j < 4; j++) acc2[i][j] = {0.f, 0.f, 0.f, 0.f};

  // ================= L1 + L2, processed in two 256-wide halves =================
  #pragma unroll 1
  for (int half = 0; half < 2; half++) {
    // ---- L1: h1[:, half*256 + w*32 .. +32) ; A gathered from global, B from W1 ----
    f32x4 acc1[4][2];
    #pragma unroll
    for (int i = 0; i < 4; i++)
      #pragma unroll
      for (int j = 0; j < 2; j++) acc1[i][j] = {0.f, 0.f, 0.f, 0.f};
    const __bf16* Bp1 = W1e + (size_t)(half * 256 + w * 32 + l16) * DIN + quad * 8;
    bf16x8 a_c[4], b_c[2], a_n[4], b_n[2];
    #pragma unroll
    for (int i = 0; i < 4; i++) a_c[i] = *(const bf16x8*)(Ap[i]);
    #pragma unroll
    for (int j = 0; j < 2; j++) b_c[j] = *(const bf16x8*)(Bp1 + j * 16 * DIN);
    #pragma unroll
    for (int s = 0; s < 8; s++) {
      if (s + 1 < 8) {
        #pragma unroll
        for (int i = 0; i < 4; i++) a_n[i] = *(const bf16x8*)(Ap[i] + (s + 1) * 32);
        #pragma unroll
        for (int j = 0; j < 2; j++) b_n[j] = *(const bf16x8*)(Bp1 + j * 16 * DIN + (s + 1) * 32);
      }
      #pragma unroll
      for (int mi = 0; mi < 4; mi++)
        #pragma unroll
        for (int ni = 0; ni < 2; ni++)
          acc1[mi][ni] = __builtin_amdgcn_mfma_f32_16x16x32_bf16(a_c[mi], b_c[ni], acc1[mi][ni], 0, 0, 0);
      if (s + 1 < 8) {
        #pragma unroll
        for (int i = 0; i < 4; i++) a_c[i] = a_n[i];
        #pragma unroll
        for (int j = 0; j < 2; j++) b_c[j] = b_n[j];
      }
    }
    if (half == 1) __syncthreads();            // L2a's reads of hbuf are done
    // write h1-half (bias+relu, bf16) into hbuf
    #pragma unroll
    for (int ni = 0; ni < 2; ni++) {
      int colg = half * 256 + w * 32 + ni * 16 + l16;
      int colb = w * 32 + ni * 16 + l16;
      float bv = b1[e * HID + colg];
      #pragma unroll
      for (int mi = 0; mi < 4; mi++)
        #pragma unroll
        for (int r = 0; r < 4; r++)
          hbuf[mi * 16 + quad * 4 + r][colb] = (__bf16)fmaxf(acc1[mi][ni][r] + bv, 0.f);
    }
    __syncthreads();
    // ---- L2 accumulate: acc2 += h1half @ W2[half*256.., wave cols w*64..+64) ----
    const __bf16* Bp2 = W2e + (size_t)(w * 64 + l16) * HID + half * 256 + quad * 8;
    bf16x8 c2[4], n2[4];
    #pragma unroll
    for (int j = 0; j < 4; j++) c2[j] = *(const bf16x8*)(Bp2 + j * 16 * HID);
    #pragma unroll
    for (int s = 0; s < 8; s++) {
      bf16x8 af[4];
      #pragma unroll
      for (int i = 0; i < 4; i++) af[i] = *(const bf16x8*)&hbuf[i * 16 + l16][quad * 8 + s * 32];
      if (s + 1 < 8) {
        #pragma unroll
        for (int j = 0; j < 4; j++) n2[j] = *(const bf16x8*)(Bp2 + j * 16 * HID + (s + 1) * 32);
      }
      #pragma unroll
      for (int mi = 0; mi < 4; mi++)
        #pragma unroll
        for (int ni = 0; ni < 4; ni++)
          acc2[mi][ni] = __builtin_amdgcn_mfma_f32_16x16x32_bf16(af[mi], c2[ni], acc2[mi][ni], 0, 0, 0);
      if (s + 1 < 8) {
        #pragma unroll
        for (int j = 0; j < 4; j++) c2[j] = n2[j];
      }
    }
  }
  __syncthreads();   // all L2b reads done; hbuf free for h2

  // ================= h2 (from acc2) + L3, in two 256-wide halves =================
  f32x4 accY[4][2];
  #pragma unroll
  for (int i = 0; i < 4; i++)
    #pragma unroll
    for (int j = 0; j < 2; j++) accY[i][j] = {0.f, 0.f, 0.f, 0.f};
  #pragma unroll 1
  for (int half = 0; half < 2; half++) {
    if ((w >> 2) == half) {                    // waves owning this half write h2 slice
      #pragma unroll
      for (int ni = 0; ni < 4; ni++) {
        int colg = w * 64 + ni * 16 + l16;     // global h2 col
        int colb = colg - half * 256;
        float bv = b2[e * HID + colg];
        #pragma unroll
        for (int mi = 0; mi < 4; mi++)
          #pragma unroll
          for (int r = 0; r < 4; r++)
            hbuf[mi * 16 + quad * 4 + r][colb] = (__bf16)fmaxf(acc2[mi][ni][r] + bv, 0.f);
      }
    }
    __syncthreads();
    const __bf16* Bp3 = W3e + (size_t)(w * 32 + l16) * HID + half * 256 + quad * 8;
    bf16x8 c3[2], n3[2];
    #pragma unroll
    for (int j = 0; j < 2; j++) c3[j] = *(const bf16x8*)(Bp3 + j * 16 * HID);
    #pragma unroll
    for (int s = 0; s < 8; s++) {
      bf16x8 af[4];
      #pragma unroll
      for (int i = 0; i < 4; i++) af[i] = *(const bf16x8*)&hbuf[i * 16 + l16][quad * 8 + s * 32];
      if (s + 1 < 8) {
        #pragma unroll
        for (int j = 0; j < 2; j++) n3[j] = *(const bf16x8*)(Bp3 + j * 16 * HID + (s + 1) * 32);
      }
      #pragma unroll
      for (int mi = 0; mi < 4; mi++)
        #pragma unroll
        for (int ni = 0; ni < 2; ni++)
          accY[mi][ni] = __builtin_amdgcn_mfma_f32_16x16x32_bf16(af[mi], c3[ni], accY[mi][ni], 0, 0, 0);
      if (s + 1 < 8) {
        #pragma unroll
        for (int j = 0; j < 2; j++) c3[j] = n3[j];
      }
    }
    if (half == 0) __syncthreads();            // L3a reads done before h2b write
  }

  // ---- epilogue: Y = accY + b3 (fp32), masked rows ----
  #pragma unroll
  for (int ni = 0; ni < 2; ni++) {
    int col = w * 32 + ni * 16 + l16;
    float bv = b3[e * DOUT + col];
    #pragma unroll
    for (int mi = 0; mi < 4; mi++)
      #pragma unroll
      for (int r = 0; r < 4; r++) {
        int row = mt * 64 + mi * 16 + quad * 4 + r;
        if (row < Te)
          Y[(size_t)(off + row) * DOUT + col] = accY[mi][ni][r] + bv;
      }
  }
}

// ---------------- final combine: out[t] = g0*Y[p0] + g1*Y[p1] ----------------
__global__ void combine_kernel(const float* __restrict__ Y, const int* __restrict__ route_pos,
                               const float2* __restrict__ g01, float* __restrict__ out) {
  int gid = blockIdx.x * blockDim.x + threadIdx.x;
  int t = gid >> 6, c = (gid & 63) << 2;
  if (t >= NTOK) return;
  int p0 = route_pos[2 * t], p1 = route_pos[2 * t + 1];
  float2 g = g01[t];
  float4 y0 = *(const float4*)&Y[(size_t)p0 * DOUT + c];
  float4 y1 = *(const float4*)&Y[(size_t)p1 * DOUT + c];
  float4 o;
  o.x = g.x * y0.x + g.y * y1.x;
  o.y = g.x * y0.y + g.y * y1.y;
  o.z = g.x * y0.z + g.y * y1.z;
  o.w = g.x * y0.w + g.y * y1.w;
  *(float4*)&out[(size_t)t * DOUT + c] = o;
}

// ---------------- launcher ----------------
extern "C" void kernel_launch(void* const* d_in, const int* in_sizes, int n_in,
                              void* d_out, int out_size, void* d_ws, size_t ws_size,
                              hipStream_t stream) {
  const float* x          = (const float*)d_in[0];
  const float* gate_w     = (const float*)d_in[1];
  const float* gate_b     = (const float*)d_in[2];
  const float* gate_out_w = (const float*)d_in[3];
  const float* gate_out_b = (const float*)d_in[4];
  const float* w1         = (const float*)d_in[5];
  const float* b1         = (const float*)d_in[6];
  const float* w2         = (const float*)d_in[7];
  const float* b2         = (const float*)d_in[8];
  const float* w3         = (const float*)d_in[9];
  const float* b3         = (const float*)d_in[10];
  float* out = (float*)d_out;

  char* ws = (char*)d_ws;
  size_t o = 0;
  auto alloc = [&](size_t bytes) -> void* {
    o = (o + 255) & ~(size_t)255;
    void* p = ws + o;
    o += bytes;
    return p;
  };

  __bf16* xb   = (__bf16*)alloc((size_t)NTOK * DIN * 2);
  __bf16* w1t  = (__bf16*)alloc((size_t)NEXP * HID * DIN * 2);
  __bf16* w2t  = (__bf16*)alloc((size_t)NEXP * HID * HID * 2);
  __bf16* w3t  = (__bf16*)alloc((size_t)NEXP * DOUT * HID * 2);
  float*  hg   = (float*)alloc((size_t)NTOK * HID * 4);
  float* logits    = (float*)alloc((size_t)NTOK * 16 * 4);
  int2*  e01       = (int2*)alloc((size_t)NTOK * 8);
  float2* g01      = (float2*)alloc((size_t)NTOK * 8);
  int*   offsets   = (int*)alloc((NEXP + 1) * 4);
  int*   blockhist = (int*)alloc((size_t)NBLK * NEXP * 4);
  int*   base      = (int*)alloc((size_t)NBLK * NEXP * 4);
  int*   lrank     = (int*)alloc((size_t)NTOK * 2 * 4);
  int*   tok_sorted= (int*)alloc((size_t)(NKA + 128) * 4);
  int*   route_pos = (int*)alloc((size_t)NTOK * 2 * 4);
  int*   tile_e    = (int*)alloc(MAXTILE * 4);
  int*   tile_mt   = (int*)alloc(MAXTILE * 4);
  int*   ntiles    = (int*)alloc(4);
  float*  Y        = (float*)alloc((size_t)(NKA + 128) * DOUT * 4);
  (void)ws_size; (void)n_in; (void)in_sizes; (void)out_size;

  dim3 tb(32, 8);
  transpose_cvt_kernel<<<dim3(DIN / 32, HID / 32, NEXP), tb, 0, stream>>>(w1, w1t, DIN, HID);
  transpose_cvt_kernel<<<dim3(HID / 32, HID / 32, NEXP), tb, 0, stream>>>(w2, w2t, HID, HID);
  transpose_cvt_kernel<<<dim3(HID / 32, DOUT / 32, NEXP), tb, 0, stream>>>(w3, w3t, HID, DOUT);

  gate_gemm_kernel<<<dim3(NTOK / 128, HID / 64), 256, 0, stream>>>(x, gate_w, gate_b, hg, xb);
  logits_kernel<<<NTOK / 8, 128, 0, stream>>>(hg, gate_out_w, gate_out_b, logits);
  top2_route_kernel<<<NBLK, 256, 0, stream>>>(logits, e01, g01, lrank, blockhist);
  scan2_kernel<<<1, 64, 0, stream>>>(blockhist, offsets, base, tile_e, tile_mt, ntiles);
  fill2_kernel<<<NBLK, 256, 0, stream>>>(e01, lrank, base, tok_sorted, route_pos);

  moe_mlp_kernel<<<MAXTILE, 512, 0, stream>>>(xb, w1t, b1, w2t, b2, w3t, b3, Y,
                                              offsets, tok_sorted, tile_e, tile_mt, ntiles);

  combine_kernel<<<(NTOK * 64) / 256, 256, 0, stream>>>(Y, route_pos, g01, out);
}